// Round 1
// baseline (29.060 us; speedup 1.0000x reference)
//
#include <hip/hip_runtime.h>

// Per-row 2D Euclidean distance, summed, divided by (B+1).
// pred/target: [B,2] float32 row-major. Output: 1 float.
// n4 = B*2/4 = 4,194,304 float4 per input.
//
// Lessons: R2 same-address device atomics serialize (+100us) -> two-kernel.
// R1 (serial loop) == R4 (flat TLP) == 28.4us -> access shape not the limiter.
// R5 (block-contiguous one-shot, 4096 blocks) = 27.1us, Occupancy only ~60%
// with nothing statically limiting it -> workgroup churn theory.
// This round: single capacity round. 2048 blocks = exactly 8 blocks/CU
// (20-32 VGPR, 4 waves/block -> 32 waves/CU), each block owns 32 KB per
// array, processed as TWO sequential 4+4 float4 batches (#pragma unroll 1
// keeps liveness ~8 float4 so VGPR stays under the 64-per-wave occupancy
// cliff). Same memset-like unit-stride 4 KB wave segments per dwordx4.

#define NBLOCKS 2048
#define NTHREADS 256
#define VPT 4      // float4 per thread per batch per array
#define NBATCH 2   // sequential batches; block footprint = 32 KB per array

__global__ __launch_bounds__(NTHREADS) void dist_partial(
    const float4* __restrict__ pred,
    const float4* __restrict__ targ,
    float* __restrict__ partials,
    int n4) {
    const int span = NTHREADS * VPT;                 // 1024 float4 per batch
    const int blockBase = blockIdx.x * (span * NBATCH);
    float s = 0.0f;

    if (blockBase + span * NBATCH <= n4) {
        #pragma unroll 1
        for (int b = 0; b < NBATCH; ++b) {
            const int base = blockBase + b * span + (int)threadIdx.x;
            float4 p0 = pred[base];
            float4 p1 = pred[base + NTHREADS];
            float4 p2 = pred[base + 2 * NTHREADS];
            float4 p3 = pred[base + 3 * NTHREADS];
            float4 t0 = targ[base];
            float4 t1 = targ[base + NTHREADS];
            float4 t2 = targ[base + 2 * NTHREADS];
            float4 t3 = targ[base + 3 * NTHREADS];
            float dx, dy;
            dx = p0.x - t0.x; dy = p0.y - t0.y; s += sqrtf(dx * dx + dy * dy);
            dx = p0.z - t0.z; dy = p0.w - t0.w; s += sqrtf(dx * dx + dy * dy);
            dx = p1.x - t1.x; dy = p1.y - t1.y; s += sqrtf(dx * dx + dy * dy);
            dx = p1.z - t1.z; dy = p1.w - t1.w; s += sqrtf(dx * dx + dy * dy);
            dx = p2.x - t2.x; dy = p2.y - t2.y; s += sqrtf(dx * dx + dy * dy);
            dx = p2.z - t2.z; dy = p2.w - t2.w; s += sqrtf(dx * dx + dy * dy);
            dx = p3.x - t3.x; dy = p3.y - t3.y; s += sqrtf(dx * dx + dy * dy);
            dx = p3.z - t3.z; dy = p3.w - t3.w; s += sqrtf(dx * dx + dy * dy);
        }
    } else {
        // Generic tail (unused at this exact shape).
        for (int b = 0; b < NBATCH; ++b) {
            #pragma unroll
            for (int k = 0; k < VPT; ++k) {
                int j = blockBase + b * span + k * NTHREADS + (int)threadIdx.x;
                if (j < n4) {
                    float4 p = pred[j];
                    float4 t = targ[j];
                    float dx0 = p.x - t.x, dy0 = p.y - t.y;
                    float dx1 = p.z - t.z, dy1 = p.w - t.w;
                    s += sqrtf(dx0 * dx0 + dy0 * dy0) +
                         sqrtf(dx1 * dx1 + dy1 * dy1);
                }
            }
        }
    }

    // Wave-64 reduction, then cross-wave via LDS.
    #pragma unroll
    for (int off = 32; off > 0; off >>= 1)
        s += __shfl_down(s, off, 64);
    __shared__ float smem[NTHREADS / 64];
    int lane = threadIdx.x & 63;
    int wave = threadIdx.x >> 6;
    if (lane == 0) smem[wave] = s;
    __syncthreads();
    if (threadIdx.x == 0) {
        float bsum = 0.0f;
        #pragma unroll
        for (int w = 0; w < NTHREADS / 64; ++w) bsum += smem[w];
        partials[blockIdx.x] = bsum;
    }
}

// Single-wave final reduction: no LDS, no __syncthreads, minimal latency.
// n4 = NBLOCKS/4 float4 (2048 floats = 512 float4 -> 8 per lane).
__global__ __launch_bounds__(64) void dist_final(
    const float4* __restrict__ partials4,
    int n4,
    float* __restrict__ out,
    float inv_np1) {
    float acc = 0.0f;
    for (int i = threadIdx.x; i < n4; i += 64) {
        float4 v = partials4[i];
        acc += (v.x + v.y) + (v.z + v.w);
    }
    #pragma unroll
    for (int off = 32; off > 0; off >>= 1)
        acc += __shfl_down(acc, off, 64);
    if (threadIdx.x == 0) out[0] = acc * inv_np1;
}

extern "C" void kernel_launch(void* const* d_in, const int* in_sizes, int n_in,
                              void* d_out, int out_size, void* d_ws, size_t ws_size,
                              hipStream_t stream) {
    const float4* pred = (const float4*)d_in[0];
    const float4* targ = (const float4*)d_in[1];
    float* out = (float*)d_out;
    float* partials = (float*)d_ws;

    long long total_floats = (long long)in_sizes[0];  // B*2
    long long n_rows = total_floats / 2;              // B
    int n4 = (int)(total_floats / 4);                 // float4 count

    float inv_np1 = 1.0f / (float)(n_rows + 1);

    dist_partial<<<NBLOCKS, NTHREADS, 0, stream>>>(pred, targ, partials, n4);
    dist_final<<<1, 64, 0, stream>>>((const float4*)partials, NBLOCKS / 4,
                                     out, inv_np1);
}